// Round 2
// baseline (641.353 us; speedup 1.0000x reference)
//
#include <hip/hip_runtime.h>

// MultiHeadAttention: x(4,2048,1024) @ W_attn(1024,3072)+b -> QKV -> causal MHA (16 heads, d=64)
// -> attn @ W_proj(1024,1024)+b. Inputs/outputs are FLOAT32; internal compute bf16 MFMA + f32 accum.
//
// Pipeline:
//   0. convert x (f32) -> xb (bf16)
//   1. transpose+convert W_attn -> Wta (3072x1024 bf16), W_proj -> Wtp (1024x1024 bf16)
//   2. GEMM1: xb(8192x1024) @ Wta^T + b_attn -> Q(B,H,T,D) K(B,H,T,D) Vt(B,H,D,T)  [bf16]
//   3. flash attention (causal), 1 wave per 16 q rows -> Ab (B,T,C) bf16
//   4. GEMM2: Ab(8192x1024) @ Wtp^T + b_proj -> out (f32)

typedef __attribute__((ext_vector_type(8))) __bf16 bf16x8;
typedef __attribute__((ext_vector_type(4))) float f32x4;
typedef __attribute__((ext_vector_type(4))) unsigned int u32x4;
typedef __attribute__((ext_vector_type(4))) short s16x4;

__device__ __forceinline__ float bf2f(unsigned short h) {
    unsigned u = ((unsigned)h) << 16;
    return __builtin_bit_cast(float, u);
}
__device__ __forceinline__ unsigned short f2bf(float f) {
    unsigned u = __builtin_bit_cast(unsigned, f);
    u += 0x7fffu + ((u >> 16) & 1u);   // RNE
    return (unsigned short)(u >> 16);
}

// ---------------- f32 -> bf16 elementwise convert (vectorized) ----------------
__global__ void convert_kernel(const float* __restrict__ in, unsigned short* __restrict__ out,
                               long n) {
    long i = ((long)blockIdx.x * blockDim.x + threadIdx.x) * 4;
    if (i >= n) return;
    f32x4 v = *reinterpret_cast<const f32x4*>(&in[i]);
    s16x4 o;
    o[0] = (short)f2bf(v[0]);
    o[1] = (short)f2bf(v[1]);
    o[2] = (short)f2bf(v[2]);
    o[3] = (short)f2bf(v[3]);
    *reinterpret_cast<s16x4*>(&out[i]) = o;
}

// ---------------- 32x32 tiled transpose+convert: Wt[n][k] = bf16(W[k][n]) ----------------
__global__ void transpose_kernel(const float* __restrict__ W,
                                 unsigned short* __restrict__ Wt,
                                 int K, int N) {
    __shared__ float t[32][33];
    const int tid = threadIdx.x;
    const int n0 = blockIdx.x * 32, k0 = blockIdx.y * 32;
    const int row = tid >> 3, c4 = (tid & 7) * 4;
    f32x4 v = *reinterpret_cast<const f32x4*>(&W[(size_t)(k0 + row) * N + n0 + c4]);
    t[row][c4 + 0] = v[0];
    t[row][c4 + 1] = v[1];
    t[row][c4 + 2] = v[2];
    t[row][c4 + 3] = v[3];
    __syncthreads();
    s16x4 o;
    o[0] = (short)f2bf(t[c4 + 0][row]);
    o[1] = (short)f2bf(t[c4 + 1][row]);
    o[2] = (short)f2bf(t[c4 + 2][row]);
    o[3] = (short)f2bf(t[c4 + 3][row]);
    *reinterpret_cast<s16x4*>(&Wt[(size_t)(n0 + row) * K + k0 + c4]) = o;
}

// ---------------- 128x128 tile MFMA GEMM, BK=32, 4 waves (2x2), 64x64/wave ----------------
// MODE 0: C = A @ Bt^T + bias  -> Cout (M x N row-major, FLOAT32)
// MODE 1: epilogue scatters QKV bf16: col<1024 -> Q(B,H,T,D), <2048 -> K(B,H,T,D), else V^T(B,H,D,T)
#define LDP 40   // padded LDS leading dim (elems); 80B stride -> <=2-way bank conflict on b128 reads

template <int MODE>
__global__ __launch_bounds__(256, 2)
void gemm_kernel(const unsigned short* __restrict__ A,
                 const unsigned short* __restrict__ Bt,
                 const float* __restrict__ bias,
                 float* __restrict__ Cout,
                 unsigned short* __restrict__ Qo,
                 unsigned short* __restrict__ Ko,
                 unsigned short* __restrict__ Vto,
                 int M, int N, int Kd) {
    __shared__ unsigned short As[128 * LDP];
    __shared__ unsigned short Bs[128 * LDP];
    const int tid = threadIdx.x;
    const int wave = tid >> 6, lane = tid & 63;
    const int l15 = lane & 15, lhi = lane >> 4;
    const int wm = wave >> 1, wn = wave & 1;
    const int m0 = blockIdx.x * 128, n0 = blockIdx.y * 128;

    f32x4 acc[4][4];
#pragma unroll
    for (int i = 0; i < 4; i++)
#pragma unroll
        for (int j = 0; j < 4; j++) acc[i][j] = f32x4{0.f, 0.f, 0.f, 0.f};

    const int r0 = tid >> 2, cb = (tid & 3) * 8;  // each thread: rows r0, r0+64; 8-elem col chunk

    for (int k0 = 0; k0 < Kd; k0 += 32) {
        u32x4 a0 = *reinterpret_cast<const u32x4*>(&A[(size_t)(m0 + r0) * Kd + k0 + cb]);
        u32x4 a1 = *reinterpret_cast<const u32x4*>(&A[(size_t)(m0 + r0 + 64) * Kd + k0 + cb]);
        u32x4 b0 = *reinterpret_cast<const u32x4*>(&Bt[(size_t)(n0 + r0) * Kd + k0 + cb]);
        u32x4 b1 = *reinterpret_cast<const u32x4*>(&Bt[(size_t)(n0 + r0 + 64) * Kd + k0 + cb]);
        *reinterpret_cast<u32x4*>(&As[r0 * LDP + cb]) = a0;
        *reinterpret_cast<u32x4*>(&As[(r0 + 64) * LDP + cb]) = a1;
        *reinterpret_cast<u32x4*>(&Bs[r0 * LDP + cb]) = b0;
        *reinterpret_cast<u32x4*>(&Bs[(r0 + 64) * LDP + cb]) = b1;
        __syncthreads();

        bf16x8 af[4], bfr[4];
#pragma unroll
        for (int i = 0; i < 4; i++) {
            af[i]  = *reinterpret_cast<const bf16x8*>(&As[(wm * 64 + i * 16 + l15) * LDP + lhi * 8]);
            bfr[i] = *reinterpret_cast<const bf16x8*>(&Bs[(wn * 64 + i * 16 + l15) * LDP + lhi * 8]);
        }
#pragma unroll
        for (int i = 0; i < 4; i++)
#pragma unroll
            for (int j = 0; j < 4; j++)
                acc[i][j] = __builtin_amdgcn_mfma_f32_16x16x32_bf16(af[i], bfr[j], acc[i][j], 0, 0, 0);
        __syncthreads();
    }

    // epilogue: D[row=(lane>>4)*4+r][col=lane&15] per 16x16 fragment
#pragma unroll
    for (int j = 0; j < 4; j++) {
        const int col = n0 + wn * 64 + j * 16 + l15;
        const float bv = bias[col];
#pragma unroll
        for (int i = 0; i < 4; i++) {
            const int rbase = m0 + wm * 64 + i * 16 + lhi * 4;
#pragma unroll
            for (int r = 0; r < 4; r++) {
                const int row = rbase + r;
                const float oval = acc[i][j][r] + bv;
                if (MODE == 0) {
                    Cout[(size_t)row * N + col] = oval;
                } else {
                    const unsigned short o = f2bf(oval);
                    const int sel = col >> 10, c1 = col & 1023;
                    const int h = c1 >> 6, d = c1 & 63;
                    const int b = row >> 11, t = row & 2047;
                    if (sel == 0)
                        Qo[(((size_t)(b * 16 + h)) * 2048 + t) * 64 + d] = o;
                    else if (sel == 1)
                        Ko[(((size_t)(b * 16 + h)) * 2048 + t) * 64 + d] = o;
                    else
                        Vto[(((size_t)(b * 16 + h)) * 64 + d) * 2048 + t] = o;
                }
            }
        }
    }
}

// ---------------- causal flash attention: 1 wave = 16 q rows, k-tiles of 32 ----------------
// Q,K: (B,H,T,64) ; Vt: (B,H,64,T) ; out Ab: (B,T,H*64)   [all bf16]
__global__ __launch_bounds__(256, 2)
void attn_kernel(const unsigned short* __restrict__ Q,
                 const unsigned short* __restrict__ Kg,
                 const unsigned short* __restrict__ Vt,
                 unsigned short* __restrict__ Aout) {
    __shared__ unsigned short Pl[4][16 * 40];   // wave-private P tile (16 q x 32 k, padded)
    const int tid = threadIdx.x, wave = tid >> 6, lane = tid & 63;
    const int l15 = lane & 15, lhi = lane >> 4;
    const int bh = blockIdx.y;                  // b*16 + h
    const int q0 = blockIdx.x * 64 + wave * 16; // this wave's first q row
    const unsigned short* Qh = Q + (size_t)bh * 2048 * 64;
    const unsigned short* Kh = Kg + (size_t)bh * 2048 * 64;
    const unsigned short* Vh = Vt + (size_t)bh * 64 * 2048;

    // Q fragments (held for the whole loop): A[q=l15][d=lhi*8+i] (+32)
    bf16x8 qa0 = *reinterpret_cast<const bf16x8*>(&Qh[(size_t)(q0 + l15) * 64 + lhi * 8]);
    bf16x8 qa1 = *reinterpret_cast<const bf16x8*>(&Qh[(size_t)(q0 + l15) * 64 + 32 + lhi * 8]);

    f32x4 o[4];
#pragma unroll
    for (int d = 0; d < 4; d++) o[d] = f32x4{0.f, 0.f, 0.f, 0.f};
    float mrow[4] = {-1e30f, -1e30f, -1e30f, -1e30f};
    float lrow[4] = {0.f, 0.f, 0.f, 0.f};
    unsigned short* P = &Pl[wave][0];

    const int ktend = q0 + 16;  // causal: need kpos <= q0+15
    for (int kt = 0; kt < ktend; kt += 32) {
        // S = Q K^T : 2 col-fragments x 2 d-halves
        f32x4 s[2];
        s[0] = f32x4{0.f, 0.f, 0.f, 0.f};
        s[1] = f32x4{0.f, 0.f, 0.f, 0.f};
#pragma unroll
        for (int nf = 0; nf < 2; nf++) {
            const unsigned short* kr = &Kh[(size_t)(kt + nf * 16 + l15) * 64 + lhi * 8];
            bf16x8 kb0 = *reinterpret_cast<const bf16x8*>(kr);
            bf16x8 kb1 = *reinterpret_cast<const bf16x8*>(kr + 32);
            s[nf] = __builtin_amdgcn_mfma_f32_16x16x32_bf16(qa0, kb0, s[nf], 0, 0, 0);
            s[nf] = __builtin_amdgcn_mfma_f32_16x16x32_bf16(qa1, kb1, s[nf], 0, 0, 0);
        }
        // scale + causal mask; row r = q0 + lhi*4 + r, col = kt + nf*16 + l15
        float tmax[4], rsum[4], corr[4];
#pragma unroll
        for (int r = 0; r < 4; r++) {
            const int qrow = q0 + lhi * 4 + r;
            float v0 = s[0][r] * 0.125f;
            float v1 = s[1][r] * 0.125f;
            if (kt + l15 > qrow) v0 = -1e30f;
            if (kt + 16 + l15 > qrow) v1 = -1e30f;
            s[0][r] = v0;
            s[1][r] = v1;
            tmax[r] = fmaxf(v0, v1);
        }
        // row max across the 16 col-lanes
#pragma unroll
        for (int m = 1; m < 16; m <<= 1)
#pragma unroll
            for (int r = 0; r < 4; r++) tmax[r] = fmaxf(tmax[r], __shfl_xor(tmax[r], m));
        // online softmax update
#pragma unroll
        for (int r = 0; r < 4; r++) {
            const float mn = fmaxf(mrow[r], tmax[r]);
            corr[r] = __expf(mrow[r] - mn);
            mrow[r] = mn;
            const float p0 = __expf(s[0][r] - mn);
            const float p1 = __expf(s[1][r] - mn);
            s[0][r] = p0;
            s[1][r] = p1;
            rsum[r] = p0 + p1;
        }
#pragma unroll
        for (int m = 1; m < 16; m <<= 1)
#pragma unroll
            for (int r = 0; r < 4; r++) rsum[r] += __shfl_xor(rsum[r], m);
#pragma unroll
        for (int r = 0; r < 4; r++) lrow[r] = lrow[r] * corr[r] + rsum[r];
#pragma unroll
        for (int d = 0; d < 4; d++)
#pragma unroll
            for (int r = 0; r < 4; r++) o[d][r] *= corr[r];

        // P (f32, D-layout) -> LDS -> A-fragment (bf16) for PV. Wave-private, no barrier:
        // all 64 lanes lockstep; lgkmcnt(0)+memory clobber orders write->read.
#pragma unroll
        for (int nf = 0; nf < 2; nf++)
#pragma unroll
            for (int r = 0; r < 4; r++)
                P[(lhi * 4 + r) * 40 + nf * 16 + l15] = f2bf(s[nf][r]);
        asm volatile("s_waitcnt lgkmcnt(0)" ::: "memory");
        bf16x8 pa = *reinterpret_cast<const bf16x8*>(&P[l15 * 40 + lhi * 8]);
#pragma unroll
        for (int db = 0; db < 4; db++) {
            bf16x8 vb = *reinterpret_cast<const bf16x8*>(&Vh[(size_t)(db * 16 + l15) * 2048 + kt + lhi * 8]);
            o[db] = __builtin_amdgcn_mfma_f32_16x16x32_bf16(pa, vb, o[db], 0, 0, 0);
        }
    }

    // epilogue: O[q][d] / l  -> Ab[b][t][h*64+d]
    const int b = bh >> 4, h = bh & 15;
#pragma unroll
    for (int r = 0; r < 4; r++) {
        const float inv = 1.0f / lrow[r];
        const int t = q0 + lhi * 4 + r;
        unsigned short* op = Aout + ((size_t)b * 2048 + t) * 1024 + h * 64;
#pragma unroll
        for (int db = 0; db < 4; db++) op[db * 16 + l15] = f2bf(o[db][r] * inv);
    }
}

extern "C" void kernel_launch(void* const* d_in, const int* in_sizes, int n_in,
                              void* d_out, int out_size, void* d_ws, size_t ws_size,
                              hipStream_t stream) {
    const float* x     = (const float*)d_in[0];
    const float* Wattn = (const float*)d_in[1];
    const float* battn = (const float*)d_in[2];
    const float* Wproj = (const float*)d_in[3];
    const float* bproj = (const float*)d_in[4];
    float* out = (float*)d_out;

    // workspace carve (bf16 elems): Q,K,Vt,Ab = 8.39M each; Wta 3.15M; Wtp 1.05M; xb 8.39M (~92 MB)
    unsigned short* ws = (unsigned short*)d_ws;
    const size_t HS = (size_t)4 * 16 * 2048 * 64;
    unsigned short* Qb  = ws;
    unsigned short* Kb  = Qb + HS;
    unsigned short* Vtb = Kb + HS;
    unsigned short* Ab  = Vtb + HS;
    unsigned short* Wta = Ab + HS;
    unsigned short* Wtp = Wta + (size_t)3072 * 1024;
    unsigned short* xb  = Wtp + (size_t)1024 * 1024;

    convert_kernel<<<8192, 256, 0, stream>>>(x, xb, (long)HS);
    transpose_kernel<<<dim3(96, 32), 256, 0, stream>>>(Wattn, Wta, 1024, 3072);
    transpose_kernel<<<dim3(32, 32), 256, 0, stream>>>(Wproj, Wtp, 1024, 1024);
    gemm_kernel<1><<<dim3(64, 24), 256, 0, stream>>>(xb, Wta, battn, nullptr, Qb, Kb, Vtb,
                                                     8192, 3072, 1024);
    attn_kernel<<<dim3(32, 64), 256, 0, stream>>>(Qb, Kb, Vtb, Ab);
    gemm_kernel<0><<<dim3(64, 8), 256, 0, stream>>>(Ab, Wtp, bproj, out, nullptr, nullptr, nullptr,
                                                    8192, 1024, 1024);
}

// Round 3
// 219.247 us; speedup vs baseline: 2.9253x; 2.9253x over previous
//
#include <hip/hip_runtime.h>

// MultiHeadAttention: x(4,2048,1024) @ W_attn(1024,3072)+b -> QKV -> causal MHA (16 heads, d=64)
// -> attn @ W_proj(1024,1024)+b. Inputs/outputs FLOAT32; internal compute bf16 MFMA + f32 accum.
//
//   0. convert x (f32) -> xb (bf16)
//   1. transpose+convert W_attn -> Wta (3072x1024 bf16), W_proj -> Wtp (1024x1024 bf16)
//   2. GEMM1: xb @ Wta^T + b_attn -> Q(B,H,T,D)*0.125, K(B,H,T,D), Vt(B,H,D,T)  [bf16]
//   3. flash attention (causal, swapped-MFMA layout), 1 wave = 64 q rows -> Ab (B,T,C) bf16
//   4. GEMM2: Ab @ Wtp^T + b_proj -> out (f32)

typedef __attribute__((ext_vector_type(8))) __bf16 bf16x8;
typedef __attribute__((ext_vector_type(4))) float f32x4;
typedef __attribute__((ext_vector_type(4))) unsigned int u32x4;
typedef __attribute__((ext_vector_type(4))) short s16x4;

__device__ __forceinline__ float bf2f(unsigned short h) {
    unsigned u = ((unsigned)h) << 16;
    return __builtin_bit_cast(float, u);
}
__device__ __forceinline__ unsigned short f2bf(float f) {
    unsigned u = __builtin_bit_cast(unsigned, f);
    u += 0x7fffu + ((u >> 16) & 1u);   // RNE
    return (unsigned short)(u >> 16);
}
__device__ __forceinline__ unsigned pack2bf(float a, float b) {
    return (unsigned)f2bf(a) | ((unsigned)f2bf(b) << 16);
}

// ---------------- f32 -> bf16 elementwise convert (vectorized) ----------------
__global__ void convert_kernel(const float* __restrict__ in, unsigned short* __restrict__ out,
                               long n) {
    long i = ((long)blockIdx.x * blockDim.x + threadIdx.x) * 4;
    if (i >= n) return;
    f32x4 v = *reinterpret_cast<const f32x4*>(&in[i]);
    s16x4 o;
    o[0] = (short)f2bf(v[0]);
    o[1] = (short)f2bf(v[1]);
    o[2] = (short)f2bf(v[2]);
    o[3] = (short)f2bf(v[3]);
    *reinterpret_cast<s16x4*>(&out[i]) = o;
}

// ---------------- 32x32 tiled transpose+convert: Wt[n][k] = bf16(W[k][n]) ----------------
__global__ void transpose_kernel(const float* __restrict__ W,
                                 unsigned short* __restrict__ Wt,
                                 int K, int N) {
    __shared__ float t[32][33];
    const int tid = threadIdx.x;
    const int n0 = blockIdx.x * 32, k0 = blockIdx.y * 32;
    const int row = tid >> 3, c4 = (tid & 7) * 4;
    f32x4 v = *reinterpret_cast<const f32x4*>(&W[(size_t)(k0 + row) * N + n0 + c4]);
    t[row][c4 + 0] = v[0];
    t[row][c4 + 1] = v[1];
    t[row][c4 + 2] = v[2];
    t[row][c4 + 3] = v[3];
    __syncthreads();
    s16x4 o;
    o[0] = (short)f2bf(t[c4 + 0][row]);
    o[1] = (short)f2bf(t[c4 + 1][row]);
    o[2] = (short)f2bf(t[c4 + 2][row]);
    o[3] = (short)f2bf(t[c4 + 3][row]);
    *reinterpret_cast<s16x4*>(&Wt[(size_t)(n0 + row) * K + k0 + c4]) = o;
}

// ---------------- 128x128 tile MFMA GEMM, BK=32, 4 waves (2x2), 64x64/wave ----------------
// MODE 0: C = A @ Bt^T + bias  -> Cout (M x N row-major, FLOAT32)
// MODE 1: scatters QKV bf16: col<1024 -> Q*0.125 (B,H,T,D), <2048 -> K(B,H,T,D), else V^T(B,H,D,T)
#define LDP 40

template <int MODE>
__global__ __launch_bounds__(256, 2)
void gemm_kernel(const unsigned short* __restrict__ A,
                 const unsigned short* __restrict__ Bt,
                 const float* __restrict__ bias,
                 float* __restrict__ Cout,
                 unsigned short* __restrict__ Qo,
                 unsigned short* __restrict__ Ko,
                 unsigned short* __restrict__ Vto,
                 int M, int N, int Kd) {
    __shared__ unsigned short As[128 * LDP];
    __shared__ unsigned short Bs[128 * LDP];
    const int tid = threadIdx.x;
    const int wave = tid >> 6, lane = tid & 63;
    const int l15 = lane & 15, lhi = lane >> 4;
    const int wm = wave >> 1, wn = wave & 1;
    const int m0 = blockIdx.x * 128, n0 = blockIdx.y * 128;

    f32x4 acc[4][4];
#pragma unroll
    for (int i = 0; i < 4; i++)
#pragma unroll
        for (int j = 0; j < 4; j++) acc[i][j] = f32x4{0.f, 0.f, 0.f, 0.f};

    const int r0 = tid >> 2, cb = (tid & 3) * 8;

    for (int k0 = 0; k0 < Kd; k0 += 32) {
        u32x4 a0 = *reinterpret_cast<const u32x4*>(&A[(size_t)(m0 + r0) * Kd + k0 + cb]);
        u32x4 a1 = *reinterpret_cast<const u32x4*>(&A[(size_t)(m0 + r0 + 64) * Kd + k0 + cb]);
        u32x4 b0 = *reinterpret_cast<const u32x4*>(&Bt[(size_t)(n0 + r0) * Kd + k0 + cb]);
        u32x4 b1 = *reinterpret_cast<const u32x4*>(&Bt[(size_t)(n0 + r0 + 64) * Kd + k0 + cb]);
        *reinterpret_cast<u32x4*>(&As[r0 * LDP + cb]) = a0;
        *reinterpret_cast<u32x4*>(&As[(r0 + 64) * LDP + cb]) = a1;
        *reinterpret_cast<u32x4*>(&Bs[r0 * LDP + cb]) = b0;
        *reinterpret_cast<u32x4*>(&Bs[(r0 + 64) * LDP + cb]) = b1;
        __syncthreads();

        bf16x8 af[4], bfr[4];
#pragma unroll
        for (int i = 0; i < 4; i++) {
            af[i]  = *reinterpret_cast<const bf16x8*>(&As[(wm * 64 + i * 16 + l15) * LDP + lhi * 8]);
            bfr[i] = *reinterpret_cast<const bf16x8*>(&Bs[(wn * 64 + i * 16 + l15) * LDP + lhi * 8]);
        }
#pragma unroll
        for (int i = 0; i < 4; i++)
#pragma unroll
            for (int j = 0; j < 4; j++)
                acc[i][j] = __builtin_amdgcn_mfma_f32_16x16x32_bf16(af[i], bfr[j], acc[i][j], 0, 0, 0);
        __syncthreads();
    }

#pragma unroll
    for (int j = 0; j < 4; j++) {
        const int col = n0 + wn * 64 + j * 16 + l15;
        const float bv = bias[col];
#pragma unroll
        for (int i = 0; i < 4; i++) {
            const int rbase = m0 + wm * 64 + i * 16 + lhi * 4;
#pragma unroll
            for (int r = 0; r < 4; r++) {
                const int row = rbase + r;
                const float oval = acc[i][j][r] + bv;
                if (MODE == 0) {
                    Cout[(size_t)row * N + col] = oval;
                } else {
                    const int sel = col >> 10, c1 = col & 1023;
                    const int h = c1 >> 6, d = c1 & 63;
                    const int b = row >> 11, t = row & 2047;
                    if (sel == 0)
                        Qo[(((size_t)(b * 16 + h)) * 2048 + t) * 64 + d] = f2bf(oval * 0.125f);
                    else if (sel == 1)
                        Ko[(((size_t)(b * 16 + h)) * 2048 + t) * 64 + d] = f2bf(oval);
                    else
                        Vto[(((size_t)(b * 16 + h)) * 64 + d) * 2048 + t] = f2bf(oval);
                }
            }
        }
    }
}

// ---------------- causal flash attention, swapped-MFMA layout ----------------
// 1 wave = 64 q rows (4 q-frags); block = 4 waves = 256 q rows; grid = 512 (head = bid&63).
// S^T = mfma(K_frag, Q_frag): q = lane&15, k = (lane>>4)*4+reg  -> row softmax is
// 15 in-register fmax + 2 shuffles. PV: O^T = mfma(V^T_frag, P^T_frag), P^T repacked
// through a wave-private padded LDS tile. No K/V staging (per-XCD resident KV ~= L2).
__global__ __launch_bounds__(256, 2)
void attn_kernel(const unsigned short* __restrict__ Q,
                 const unsigned short* __restrict__ Kg,
                 const unsigned short* __restrict__ Vt,
                 unsigned short* __restrict__ Aout) {
    __shared__ unsigned int Pl[4][16 * 36];     // per-wave P^T tile: [q=16][k=64] bf16, 144B rows
    const int tid = threadIdx.x, wave = tid >> 6, lane = tid & 63;
    const int l15 = lane & 15, lhi = lane >> 4;
    const int bid = blockIdx.x;
    const int head = bid & 63;
    const int j = bid >> 6;
    const int qb = (j < 4) ? j : (11 - j);       // complement pairing: qb(j)+qb(j+4)=7
    const int q0w = qb * 256 + wave * 64;
    const unsigned short* Qh = Q + (size_t)head * (2048 * 64);
    const unsigned short* Kh = Kg + (size_t)head * (2048 * 64);
    const unsigned short* Vh = Vt + (size_t)head * (64 * 2048);
    unsigned int* P = &Pl[wave][0];

    // Q B-frags (pre-scaled by 0.125 in GEMM1): [qf][dh] = Q[q0w+qf*16+l15][dh*32+lhi*8 ..+7]
    bf16x8 qfr[4][2];
#pragma unroll
    for (int qf = 0; qf < 4; qf++)
#pragma unroll
        for (int dh = 0; dh < 2; dh++)
            qfr[qf][dh] = *reinterpret_cast<const bf16x8*>(
                &Qh[(size_t)(q0w + qf * 16 + l15) * 64 + dh * 32 + lhi * 8]);

    f32x4 o[4][4];   // [df][qf], O^T[d=df*16+lhi*4+r][q=qf*16+l15]
#pragma unroll
    for (int df = 0; df < 4; df++)
#pragma unroll
        for (int qf = 0; qf < 4; qf++) o[df][qf] = f32x4{0.f, 0.f, 0.f, 0.f};
    float m[4] = {-1e30f, -1e30f, -1e30f, -1e30f};
    float l[4] = {0.f, 0.f, 0.f, 0.f};

    const int ntiles = (q0w >> 6) + 1;
    for (int t = 0; t < ntiles; ++t) {
        const int kt = t * 64;
        const bool masked = (t == ntiles - 1);
        // K frags [kf][dh]: K[kt+kf*16+l15][dh*32+lhi*8..]; V frags [df][kc]: Vt[df*16+l15][kt+kc*32+lhi*8..]
        bf16x8 kfr[4][2], vfr[4][2];
#pragma unroll
        for (int kf = 0; kf < 4; kf++)
#pragma unroll
            for (int dh = 0; dh < 2; dh++)
                kfr[kf][dh] = *reinterpret_cast<const bf16x8*>(
                    &Kh[(size_t)(kt + kf * 16 + l15) * 64 + dh * 32 + lhi * 8]);
#pragma unroll
        for (int df = 0; df < 4; df++)
#pragma unroll
            for (int kc = 0; kc < 2; kc++)
                vfr[df][kc] = *reinterpret_cast<const bf16x8*>(
                    &Vh[(size_t)(df * 16 + l15) * 2048 + kt + kc * 32 + lhi * 8]);

#pragma unroll
        for (int qf = 0; qf < 4; qf++) {
            f32x4 s[4];
#pragma unroll
            for (int kf = 0; kf < 4; kf++) {
                s[kf] = __builtin_amdgcn_mfma_f32_16x16x32_bf16(kfr[kf][0], qfr[qf][0],
                                                                f32x4{0.f, 0.f, 0.f, 0.f}, 0, 0, 0);
                s[kf] = __builtin_amdgcn_mfma_f32_16x16x32_bf16(kfr[kf][1], qfr[qf][1], s[kf], 0, 0, 0);
            }
            if (masked) {
                // q_loc = qf*16 + l15, k_loc = kf*16 + lhi*4 + r  (tile-local; kt == q0w here)
#pragma unroll
                for (int kf = 0; kf < 4; kf++)
#pragma unroll
                    for (int r = 0; r < 4; r++)
                        if (kf * 16 + lhi * 4 + r > qf * 16 + l15) s[kf][r] = -1e30f;
            }
            float tm = s[0][0];
#pragma unroll
            for (int kf = 0; kf < 4; kf++)
#pragma unroll
                for (int r = 0; r < 4; r++) tm = fmaxf(tm, s[kf][r]);
            tm = fmaxf(tm, __shfl_xor(tm, 16));
            tm = fmaxf(tm, __shfl_xor(tm, 32));
            const float mn = fmaxf(m[qf], tm);
            const float corr = __expf(m[qf] - mn);
            m[qf] = mn;
            float rs = 0.f;
#pragma unroll
            for (int kf = 0; kf < 4; kf++)
#pragma unroll
                for (int r = 0; r < 4; r++) {
                    const float p = __expf(s[kf][r] - mn);
                    s[kf][r] = p;
                    rs += p;
                }
            rs += __shfl_xor(rs, 16);
            rs += __shfl_xor(rs, 32);
            l[qf] = l[qf] * corr + rs;
#pragma unroll
            for (int df = 0; df < 4; df++)
#pragma unroll
                for (int r = 0; r < 4; r++) o[df][qf][r] *= corr;

            // pack P^T -> LDS [q=l15][k]: word (k-pair) offset = kf*8 + lhi*2 + j
#pragma unroll
            for (int kf = 0; kf < 4; kf++) {
                P[l15 * 36 + kf * 8 + lhi * 2 + 0] = pack2bf(s[kf][0], s[kf][1]);
                P[l15 * 36 + kf * 8 + lhi * 2 + 1] = pack2bf(s[kf][2], s[kf][3]);
            }
            asm volatile("s_waitcnt lgkmcnt(0)" ::: "memory");
            bf16x8 pb0 = *reinterpret_cast<const bf16x8*>(&P[l15 * 36 + 0 * 16 + lhi * 4]);
            bf16x8 pb1 = *reinterpret_cast<const bf16x8*>(&P[l15 * 36 + 1 * 16 + lhi * 4]);
#pragma unroll
            for (int df = 0; df < 4; df++) {
                o[df][qf] = __builtin_amdgcn_mfma_f32_16x16x32_bf16(vfr[df][0], pb0, o[df][qf], 0, 0, 0);
                o[df][qf] = __builtin_amdgcn_mfma_f32_16x16x32_bf16(vfr[df][1], pb1, o[df][qf], 0, 0, 0);
            }
        }
    }

    // epilogue: O^T[d][q]/l -> Ab[b][t=q0w+qf*16+l15][h*64 + d], d = df*16+lhi*4+r
    const int b = head >> 4, h = head & 15;
#pragma unroll
    for (int qf = 0; qf < 4; qf++) {
        const float inv = 1.0f / l[qf];
        unsigned short* op = Aout + ((size_t)(b * 2048 + q0w + qf * 16 + l15)) * 1024 + h * 64;
#pragma unroll
        for (int df = 0; df < 4; df++) {
            *reinterpret_cast<unsigned*>(&op[df * 16 + lhi * 4]) =
                pack2bf(o[df][qf][0] * inv, o[df][qf][1] * inv);
            *reinterpret_cast<unsigned*>(&op[df * 16 + lhi * 4 + 2]) =
                pack2bf(o[df][qf][2] * inv, o[df][qf][3] * inv);
        }
    }
}

extern "C" void kernel_launch(void* const* d_in, const int* in_sizes, int n_in,
                              void* d_out, int out_size, void* d_ws, size_t ws_size,
                              hipStream_t stream) {
    const float* x     = (const float*)d_in[0];
    const float* Wattn = (const float*)d_in[1];
    const float* battn = (const float*)d_in[2];
    const float* Wproj = (const float*)d_in[3];
    const float* bproj = (const float*)d_in[4];
    float* out = (float*)d_out;

    unsigned short* ws = (unsigned short*)d_ws;
    const size_t HS = (size_t)4 * 16 * 2048 * 64;
    unsigned short* Qb  = ws;
    unsigned short* Kb  = Qb + HS;
    unsigned short* Vtb = Kb + HS;
    unsigned short* Ab  = Vtb + HS;
    unsigned short* Wta = Ab + HS;
    unsigned short* Wtp = Wta + (size_t)3072 * 1024;
    unsigned short* xb  = Wtp + (size_t)1024 * 1024;

    convert_kernel<<<8192, 256, 0, stream>>>(x, xb, (long)HS);
    transpose_kernel<<<dim3(96, 32), 256, 0, stream>>>(Wattn, Wta, 1024, 3072);
    transpose_kernel<<<dim3(32, 32), 256, 0, stream>>>(Wproj, Wtp, 1024, 1024);
    gemm_kernel<1><<<dim3(64, 24), 256, 0, stream>>>(xb, Wta, battn, nullptr, Qb, Kb, Vtb,
                                                     8192, 3072, 1024);
    attn_kernel<<<512, 256, 0, stream>>>(Qb, Kb, Vtb, Ab);
    gemm_kernel<0><<<dim3(64, 8), 256, 0, stream>>>(Ab, Wtp, bproj, out, nullptr, nullptr, nullptr,
                                                    8192, 1024, 1024);
}